// Round 1
// baseline (63.985 us; speedup 1.0000x reference)
//
#include <hip/hip_runtime.h>

#define W_LEN 4
#define OUT_C 3
#define KK    3
#define HH    16
#define FC_HID 6
#define W_NEW 2          // W_LEN - K + 1
#define FC_IN 96         // OUT_C * W_NEW * HH
#define TT    16384
#define BB    32

__device__ __forceinline__ float tanh_fast(float x) {
    // tanh(x) = 1 - 2/(exp(2x)+1); v_exp_f32 + v_rcp_f32, saturates correctly at +-inf
    float e = __expf(2.0f * x);
    return 1.0f - __fdividef(2.0f, e + 1.0f);
}

__global__ __launch_bounds__(256) void rvtdcnn_fused(
    const float* __restrict__ x,
    const float* __restrict__ conv_w,
    const float* __restrict__ conv_b,
    const float* __restrict__ fc_hid_w,
    const float* __restrict__ fc_hid_b,
    const float* __restrict__ fc_out_w,
    const float* __restrict__ fc_out_b,
    float* __restrict__ out)
{
    const int gid = blockIdx.x * blockDim.x + threadIdx.x;   // position in [0, B*T)
    const int b = gid >> 14;          // / TT
    const int t = gid & (TT - 1);     // % TT

    // ---- load 4x16 window into registers (causal: rows t-3..t, zero-padded) ----
    float I[W_LEN][HH];
    const float4* x4 = reinterpret_cast<const float4*>(x);
    #pragma unroll
    for (int r = 0; r < W_LEN; ++r) {
        int tr = t - (W_LEN - 1) + r;
        if (tr < 0) {
            #pragma unroll
            for (int c = 0; c < HH; ++c) I[r][c] = 0.0f;
        } else {
            int base = (b * TT + tr) * (HH / 4);
            #pragma unroll
            for (int q = 0; q < HH / 4; ++q) {
                float4 v = x4[base + q];
                I[r][q * 4 + 0] = v.x;
                I[r][q * 4 + 1] = v.y;
                I[r][q * 4 + 2] = v.z;
                I[r][q * 4 + 3] = v.w;
            }
        }
    }

    // ---- conv weights (wave-uniform -> scalar regs) ----
    float cw[OUT_C][KK][KK];
    #pragma unroll
    for (int oc = 0; oc < OUT_C; ++oc)
        #pragma unroll
        for (int kr = 0; kr < KK; ++kr)
            #pragma unroll
            for (int kc = 0; kc < KK; ++kc)
                cw[oc][kr][kc] = conv_w[(oc * KK + kr) * KK + kc];
    float cb[OUT_C];
    #pragma unroll
    for (int oc = 0; oc < OUT_C; ++oc) cb[oc] = conv_b[oc];

    // ---- fused conv -> tanh -> FC1 accumulation ----
    float h[FC_HID];
    #pragma unroll
    for (int j = 0; j < FC_HID; ++j) h[j] = fc_hid_b[j];

    #pragma unroll
    for (int oc = 0; oc < OUT_C; ++oc) {
        #pragma unroll
        for (int wr = 0; wr < W_NEW; ++wr) {
            #pragma unroll
            for (int c = 0; c < HH; ++c) {
                float acc = cb[oc];
                #pragma unroll
                for (int kr = 0; kr < KK; ++kr) {
                    #pragma unroll
                    for (int kc = 0; kc < KK; ++kc) {
                        int cc = c + kc - 1;
                        if (cc >= 0 && cc < HH)
                            acc += I[wr + kr][cc] * cw[oc][kr][kc];
                    }
                }
                float f = tanh_fast(acc);
                const int idx = (oc * W_NEW + wr) * HH + c;   // reshape order (OC, W_NEW, H)
                #pragma unroll
                for (int j = 0; j < FC_HID; ++j)
                    h[j] += f * fc_hid_w[j * FC_IN + idx];    // uniform addr -> s_load
            }
        }
    }

    // ---- FC1 tanh -> FC2 ----
    float y0 = fc_out_b[0];
    float y1 = fc_out_b[1];
    #pragma unroll
    for (int j = 0; j < FC_HID; ++j) {
        float hj = tanh_fast(h[j]);
        y0 += hj * fc_out_w[j];
        y1 += hj * fc_out_w[FC_HID + j];
    }

    float2* out2 = reinterpret_cast<float2*>(out);
    out2[gid] = make_float2(y0, y1);
}

extern "C" void kernel_launch(void* const* d_in, const int* in_sizes, int n_in,
                              void* d_out, int out_size, void* d_ws, size_t ws_size,
                              hipStream_t stream) {
    const float* x        = (const float*)d_in[0];
    const float* conv_w   = (const float*)d_in[1];
    const float* conv_b   = (const float*)d_in[2];
    const float* fc_hid_w = (const float*)d_in[3];
    const float* fc_hid_b = (const float*)d_in[4];
    const float* fc_out_w = (const float*)d_in[5];
    const float* fc_out_b = (const float*)d_in[6];
    float* out = (float*)d_out;

    const int n = BB * TT;                 // 524288 positions
    const int block = 256;
    const int grid = n / block;            // 2048 blocks, exact
    rvtdcnn_fused<<<grid, block, 0, stream>>>(x, conv_w, conv_b, fc_hid_w, fc_hid_b,
                                              fc_out_w, fc_out_b, out);
}

// Round 2
// 51.160 us; speedup vs baseline: 1.2507x; 1.2507x over previous
//
#include <hip/hip_runtime.h>

#define W_LEN 4
#define OUT_C 3
#define KK    3
#define HH    16
#define FC_HID 6
#define W_NEW 2          // W_LEN - K + 1
#define FC_IN 96         // OUT_C * W_NEW * HH
#define TT    16384
#define BB    32

__device__ __forceinline__ float tanh_fast(float x) {
    // tanh(x) = 1 - 2/(exp(2x)+1): v_mul, v_exp, v_add, v_rcp, v_fma (2 transcendentals)
    float e = __expf(2.0f * x);
    float r = __builtin_amdgcn_rcpf(e + 1.0f);
    return fmaf(-2.0f, r, 1.0f);
}

// Each thread computes TWO consecutive time positions (t0, t0+1).
// Conv-row reuse: conv row over input rows (t-2..t) serves as wr=1 for pos t
// and wr=0 for pos t+1 -> 3 conv rows instead of 4 for the pair.
__global__ __launch_bounds__(256, 4) void rvtdcnn_fused2(
    const float* __restrict__ x,
    const float* __restrict__ conv_w,
    const float* __restrict__ conv_b,
    const float* __restrict__ fc_hid_w,
    const float* __restrict__ fc_hid_b,
    const float* __restrict__ fc_out_w,
    const float* __restrict__ fc_out_b,
    float* __restrict__ out)
{
    const int gid = blockIdx.x * blockDim.x + threadIdx.x;   // [0, B*T/2)
    const int b  = gid >> 13;            // / (TT/2)
    const int t0 = (gid & 8191) << 1;    // even position

    // ---- input rows t0-3 .. t0+1 (5 rows), zero-padded below t=0 ----
    float R[5][HH];
    const float4* x4 = reinterpret_cast<const float4*>(x);
    #pragma unroll
    for (int r = 0; r < 5; ++r) {
        const int tr = t0 - 3 + r;
        if (tr < 0) {
            #pragma unroll
            for (int c = 0; c < HH; ++c) R[r][c] = 0.0f;
        } else {
            const int base = (b * TT + tr) * (HH / 4);
            #pragma unroll
            for (int q = 0; q < HH / 4; ++q) {
                float4 v = x4[base + q];
                R[r][q * 4 + 0] = v.x;
                R[r][q * 4 + 1] = v.y;
                R[r][q * 4 + 2] = v.z;
                R[r][q * 4 + 3] = v.w;
            }
        }
    }

    // ---- conv weights (wave-uniform addresses -> scalar regs) ----
    float cw[OUT_C][KK][KK];
    #pragma unroll
    for (int oc = 0; oc < OUT_C; ++oc)
        #pragma unroll
        for (int kr = 0; kr < KK; ++kr)
            #pragma unroll
            for (int kc = 0; kc < KK; ++kc)
                cw[oc][kr][kc] = conv_w[(oc * KK + kr) * KK + kc];
    float cb[OUT_C];
    #pragma unroll
    for (int oc = 0; oc < OUT_C; ++oc) cb[oc] = conv_b[oc];

    // ---- two FC1 accumulator sets (pos t0 and t0+1) ----
    float h_a[FC_HID], h_b[FC_HID];
    #pragma unroll
    for (int j = 0; j < FC_HID; ++j) {
        const float bj = fc_hid_b[j];
        h_a[j] = bj;
        h_b[j] = bj;
    }

    // ---- 3 conv rows; each feature immediately scattered into h_a/h_b ----
    // crow 0: input rows (t0-3..t0-1) -> pos t0 wr=0
    // crow 1: input rows (t0-2..t0)   -> pos t0 wr=1  AND  pos t0+1 wr=0
    // crow 2: input rows (t0-1..t0+1) -> pos t0+1 wr=1
    #pragma unroll
    for (int crow = 0; crow < 3; ++crow) {
        #pragma unroll
        for (int oc = 0; oc < OUT_C; ++oc) {
            #pragma unroll
            for (int c = 0; c < HH; ++c) {
                float acc = cb[oc];
                #pragma unroll
                for (int kr = 0; kr < KK; ++kr) {
                    #pragma unroll
                    for (int kc = 0; kc < KK; ++kc) {
                        const int cc = c + kc - 1;
                        if (cc >= 0 && cc < HH)
                            acc = fmaf(R[crow + kr][cc], cw[oc][kr][kc], acc);
                    }
                }
                const float f = tanh_fast(acc);
                const int i0 = (oc * W_NEW + 0) * HH + c;   // wr=0 slot
                const int i1 = (oc * W_NEW + 1) * HH + c;   // wr=1 slot
                if (crow == 0) {
                    #pragma unroll
                    for (int j = 0; j < FC_HID; ++j)
                        h_a[j] = fmaf(f, fc_hid_w[j * FC_IN + i0], h_a[j]);
                } else if (crow == 1) {
                    #pragma unroll
                    for (int j = 0; j < FC_HID; ++j)
                        h_a[j] = fmaf(f, fc_hid_w[j * FC_IN + i1], h_a[j]);
                    #pragma unroll
                    for (int j = 0; j < FC_HID; ++j)
                        h_b[j] = fmaf(f, fc_hid_w[j * FC_IN + i0], h_b[j]);
                } else {
                    #pragma unroll
                    for (int j = 0; j < FC_HID; ++j)
                        h_b[j] = fmaf(f, fc_hid_w[j * FC_IN + i1], h_b[j]);
                }
            }
        }
    }

    // ---- FC1 tanh -> FC2 for both positions ----
    float ya0 = fc_out_b[0], ya1 = fc_out_b[1];
    float yb0 = ya0, yb1 = ya1;
    #pragma unroll
    for (int j = 0; j < FC_HID; ++j) {
        const float w0 = fc_out_w[j];
        const float w1 = fc_out_w[FC_HID + j];
        const float ha = tanh_fast(h_a[j]);
        const float hb = tanh_fast(h_b[j]);
        ya0 = fmaf(ha, w0, ya0);
        ya1 = fmaf(ha, w1, ya1);
        yb0 = fmaf(hb, w0, yb0);
        yb1 = fmaf(hb, w1, yb1);
    }

    // out floats 2*(b*TT+t0) .. +3 -> one aligned float4 (t0 even)
    float4 o;
    o.x = ya0; o.y = ya1; o.z = yb0; o.w = yb1;
    reinterpret_cast<float4*>(out)[(b * TT + t0) >> 1] = o;
}

extern "C" void kernel_launch(void* const* d_in, const int* in_sizes, int n_in,
                              void* d_out, int out_size, void* d_ws, size_t ws_size,
                              hipStream_t stream) {
    const float* x        = (const float*)d_in[0];
    const float* conv_w   = (const float*)d_in[1];
    const float* conv_b   = (const float*)d_in[2];
    const float* fc_hid_w = (const float*)d_in[3];
    const float* fc_hid_b = (const float*)d_in[4];
    const float* fc_out_w = (const float*)d_in[5];
    const float* fc_out_b = (const float*)d_in[6];
    float* out = (float*)d_out;

    const int n_pairs = BB * TT / 2;       // 262144 threads
    const int block = 256;
    const int grid = n_pairs / block;      // 1024 blocks -> 4 blocks/CU, uniform
    rvtdcnn_fused2<<<grid, block, 0, stream>>>(x, conv_w, conv_b, fc_hid_w, fc_hid_b,
                                               fc_out_w, fc_out_b, out);
}

// Round 3
// 46.210 us; speedup vs baseline: 1.3847x; 1.1071x over previous
//
#include <hip/hip_runtime.h>

#define W_LEN 4
#define OUT_C 3
#define KK    3
#define HH    16
#define FC_HID 6
#define W_NEW 2          // W_LEN - K + 1
#define FC_IN 96         // OUT_C * W_NEW * HH
#define TT    16384
#define BB    32

__device__ __forceinline__ float tanh_fast(float x) {
    // tanh(x) = 1 - 2/(exp(2x)+1): 3 regular VALU + 2 transcendental
    float e = __expf(2.0f * x);
    float r = __builtin_amdgcn_rcpf(e + 1.0f);
    return fmaf(-2.0f, r, 1.0f);
}

// Two consecutive positions per thread; 3 conv rows per pair (row reuse).
// Rows held as five NAMED 16-float arrays consumed in a sliding pattern so the
// peak live set fits the 128-VGPR budget pinned by amdgpu_waves_per_eu(4,4).
__global__ __launch_bounds__(256)
__attribute__((amdgpu_waves_per_eu(4, 4)))
void rvtdcnn_fused3(
    const float* __restrict__ x,
    const float* __restrict__ conv_w,
    const float* __restrict__ conv_b,
    const float* __restrict__ fc_hid_w,
    const float* __restrict__ fc_hid_b,
    const float* __restrict__ fc_out_w,
    const float* __restrict__ fc_out_b,
    float* __restrict__ out)
{
    const int gid = blockIdx.x * blockDim.x + threadIdx.x;   // [0, B*T/2)
    const int b  = gid >> 13;            // / (TT/2)
    const int t0 = (gid & 8191) << 1;    // even position

    // float4 base at (b, t0); row offsets -3..+1 are relative float4 offsets *4
    const float4* x4 = reinterpret_cast<const float4*>(x) + (size_t)(b * TT + t0) * (HH / 4);

#define LOAD_ROW(R, OFF)                                                     \
    do {                                                                     \
        if (t0 + (OFF) < 0) {                                                \
            _Pragma("unroll") for (int c = 0; c < HH; ++c) R[c] = 0.0f;      \
        } else {                                                             \
            _Pragma("unroll") for (int q = 0; q < HH / 4; ++q) {             \
                float4 v = x4[(OFF) * (HH / 4) + q];                         \
                R[q * 4 + 0] = v.x; R[q * 4 + 1] = v.y;                      \
                R[q * 4 + 2] = v.z; R[q * 4 + 3] = v.w;                      \
            }                                                                \
        }                                                                    \
    } while (0)

    // ---- conv weights (wave-uniform -> scalar regs) ----
    float cw[OUT_C][KK][KK];
    #pragma unroll
    for (int oc = 0; oc < OUT_C; ++oc)
        #pragma unroll
        for (int kr = 0; kr < KK; ++kr)
            #pragma unroll
            for (int kc = 0; kc < KK; ++kc)
                cw[oc][kr][kc] = conv_w[(oc * KK + kr) * KK + kc];
    float cb[OUT_C];
    #pragma unroll
    for (int oc = 0; oc < OUT_C; ++oc) cb[oc] = conv_b[oc];

    float h_a[FC_HID], h_b[FC_HID];
    #pragma unroll
    for (int j = 0; j < FC_HID; ++j) {
        const float bj = fc_hid_b[j];
        h_a[j] = bj;
        h_b[j] = bj;
    }

    // CONV_ROW over named rows RA,RB,RC (kr=0,1,2).
    // DO_A/IA: scatter feature into h_a at wr-slot IA; DO_B/IB likewise for h_b.
#define CONV_ROW(RA, RB, RC, DO_A, IA, DO_B, IB)                             \
    _Pragma("unroll") for (int oc = 0; oc < OUT_C; ++oc) {                   \
        _Pragma("unroll") for (int c = 0; c < HH; ++c) {                     \
            float acc = cb[oc];                                              \
            _Pragma("unroll") for (int kc = 0; kc < KK; ++kc) {              \
                const int cc = c + kc - 1;                                   \
                if (cc >= 0 && cc < HH) {                                    \
                    acc = fmaf(RA[cc], cw[oc][0][kc], acc);                  \
                    acc = fmaf(RB[cc], cw[oc][1][kc], acc);                  \
                    acc = fmaf(RC[cc], cw[oc][2][kc], acc);                  \
                }                                                            \
            }                                                                \
            const float f = tanh_fast(acc);                                  \
            if (DO_A) {                                                      \
                const int ia = (oc * W_NEW + (IA)) * HH + c;                 \
                _Pragma("unroll") for (int j = 0; j < FC_HID; ++j)           \
                    h_a[j] = fmaf(f, fc_hid_w[j * FC_IN + ia], h_a[j]);      \
            }                                                                \
            if (DO_B) {                                                      \
                const int ib = (oc * W_NEW + (IB)) * HH + c;                 \
                _Pragma("unroll") for (int j = 0; j < FC_HID; ++j)           \
                    h_b[j] = fmaf(f, fc_hid_w[j * FC_IN + ib], h_b[j]);      \
            }                                                                \
        }                                                                    \
    }

    float r0[HH], r1[HH], r2[HH], r3[HH], r4[HH];
    LOAD_ROW(r0, -3);
    LOAD_ROW(r1, -2);
    LOAD_ROW(r2, -1);
    LOAD_ROW(r3,  0);

    // crow0: rows (t0-3..t0-1) -> pos t0 wr=0          (r0 dies after this)
    CONV_ROW(r0, r1, r2, true, 0, false, 0);
    LOAD_ROW(r4, 1);
    // crow1: rows (t0-2..t0)   -> pos t0 wr=1, pos t0+1 wr=0   (r1 dies)
    CONV_ROW(r1, r2, r3, true, 1, true, 0);
    // crow2: rows (t0-1..t0+1) -> pos t0+1 wr=1
    CONV_ROW(r2, r3, r4, false, 0, true, 1);

    // ---- FC1 tanh -> FC2 for both positions ----
    float ya0 = fc_out_b[0], ya1 = fc_out_b[1];
    float yb0 = ya0, yb1 = ya1;
    #pragma unroll
    for (int j = 0; j < FC_HID; ++j) {
        const float w0 = fc_out_w[j];
        const float w1 = fc_out_w[FC_HID + j];
        const float ha = tanh_fast(h_a[j]);
        const float hb = tanh_fast(h_b[j]);
        ya0 = fmaf(ha, w0, ya0);
        ya1 = fmaf(ha, w1, ya1);
        yb0 = fmaf(hb, w0, yb0);
        yb1 = fmaf(hb, w1, yb1);
    }

    float4 o;
    o.x = ya0; o.y = ya1; o.z = yb0; o.w = yb1;
    reinterpret_cast<float4*>(out)[(b * TT + t0) >> 1] = o;

#undef LOAD_ROW
#undef CONV_ROW
}

extern "C" void kernel_launch(void* const* d_in, const int* in_sizes, int n_in,
                              void* d_out, int out_size, void* d_ws, size_t ws_size,
                              hipStream_t stream) {
    const float* x        = (const float*)d_in[0];
    const float* conv_w   = (const float*)d_in[1];
    const float* conv_b   = (const float*)d_in[2];
    const float* fc_hid_w = (const float*)d_in[3];
    const float* fc_hid_b = (const float*)d_in[4];
    const float* fc_out_w = (const float*)d_in[5];
    const float* fc_out_b = (const float*)d_in[6];
    float* out = (float*)d_out;

    const int n_pairs = BB * TT / 2;       // 262144 threads
    const int block = 256;
    const int grid = n_pairs / block;      // 1024 blocks = 4 blocks/CU, uniform
    rvtdcnn_fused3<<<grid, block, 0, stream>>>(x, conv_w, conv_b, fc_hid_w, fc_hid_b,
                                               fc_out_w, fc_out_b, out);
}

// Round 4
// 32.958 us; speedup vs baseline: 1.9414x; 1.4021x over previous
//
#include <hip/hip_runtime.h>

#define W_LEN 4
#define OUT_C 3
#define KK    3
#define HH    16
#define FC_HID 6
#define W_NEW 2          // W_LEN - K + 1
#define FC_IN 96         // OUT_C * W_NEW * HH
#define TT    16384
#define BB    32

__device__ __forceinline__ float tanh_fast(float x) {
    // tanh(x) = 1 - 2/(2^(x*2*log2e)+1): mul, exp2, add, rcp, fma
    float e = __builtin_amdgcn_exp2f(x * 2.8853900817779268f);
    float r = __builtin_amdgcn_rcpf(e + 1.0f);
    return fmaf(-2.0f, r, 1.0f);
}

// Two consecutive positions per thread; 3 conv rows per pair (row reuse).
// FOUR row slots: after crow0 consumes row(t0-3), its slot is reloaded with
// row(t0+1) (WAR dep through SSA keeps peak live at 4 rows = 64 floats).
// __launch_bounds__(256,2): min 2 waves/EU -> 256-VGPR budget, pressure-driven
// allocation (round-2/3's min=4 made the allocator spill to reach 8 waves/EU
// that the 4-blocks/CU dispatch never uses).
__global__ __launch_bounds__(256, 2)
void rvtdcnn_fused4(
    const float* __restrict__ x,
    const float* __restrict__ conv_w,
    const float* __restrict__ conv_b,
    const float* __restrict__ fc_hid_w,
    const float* __restrict__ fc_hid_b,
    const float* __restrict__ fc_out_w,
    const float* __restrict__ fc_out_b,
    float* __restrict__ out)
{
    const int gid = blockIdx.x * blockDim.x + threadIdx.x;   // [0, B*T/2)
    const int b  = gid >> 13;            // / (TT/2)
    const int t0 = (gid & 8191) << 1;    // even position

    const float4* x4 = reinterpret_cast<const float4*>(x) + (size_t)(b * TT + t0) * (HH / 4);

#define LOAD_ROW(R, OFF)                                                     \
    do {                                                                     \
        if (t0 + (OFF) < 0) {                                                \
            _Pragma("unroll") for (int c = 0; c < HH; ++c) R[c] = 0.0f;      \
        } else {                                                             \
            _Pragma("unroll") for (int q = 0; q < HH / 4; ++q) {             \
                float4 v = x4[(OFF) * (HH / 4) + q];                         \
                R[q * 4 + 0] = v.x; R[q * 4 + 1] = v.y;                      \
                R[q * 4 + 2] = v.z; R[q * 4 + 3] = v.w;                      \
            }                                                                \
        }                                                                    \
    } while (0)

    // ---- conv weights (wave-uniform addresses -> scalar regs) ----
    float cw[OUT_C][KK][KK];
    #pragma unroll
    for (int oc = 0; oc < OUT_C; ++oc)
        #pragma unroll
        for (int kr = 0; kr < KK; ++kr)
            #pragma unroll
            for (int kc = 0; kc < KK; ++kc)
                cw[oc][kr][kc] = conv_w[(oc * KK + kr) * KK + kc];
    float cb[OUT_C];
    #pragma unroll
    for (int oc = 0; oc < OUT_C; ++oc) cb[oc] = conv_b[oc];

    float h_a[FC_HID], h_b[FC_HID];
    #pragma unroll
    for (int j = 0; j < FC_HID; ++j) {
        const float bj = fc_hid_b[j];
        h_a[j] = bj;
        h_b[j] = bj;
    }

#define CONV_ROW(RA, RB, RC, DO_A, IA, DO_B, IB)                             \
    _Pragma("unroll") for (int oc = 0; oc < OUT_C; ++oc) {                   \
        _Pragma("unroll") for (int c = 0; c < HH; ++c) {                     \
            float acc = cb[oc];                                              \
            _Pragma("unroll") for (int kc = 0; kc < KK; ++kc) {              \
                const int cc = c + kc - 1;                                   \
                if (cc >= 0 && cc < HH) {                                    \
                    acc = fmaf(RA[cc], cw[oc][0][kc], acc);                  \
                    acc = fmaf(RB[cc], cw[oc][1][kc], acc);                  \
                    acc = fmaf(RC[cc], cw[oc][2][kc], acc);                  \
                }                                                            \
            }                                                                \
            const float f = tanh_fast(acc);                                  \
            if (DO_A) {                                                      \
                const int ia = (oc * W_NEW + (IA)) * HH + c;                 \
                _Pragma("unroll") for (int j = 0; j < FC_HID; ++j)           \
                    h_a[j] = fmaf(f, fc_hid_w[j * FC_IN + ia], h_a[j]);      \
            }                                                                \
            if (DO_B) {                                                      \
                const int ib = (oc * W_NEW + (IB)) * HH + c;                 \
                _Pragma("unroll") for (int j = 0; j < FC_HID; ++j)           \
                    h_b[j] = fmaf(f, fc_hid_w[j * FC_IN + ib], h_b[j]);      \
            }                                                                \
        }                                                                    \
    }

    float rA[HH], rB[HH], rC[HH], rD[HH];
    LOAD_ROW(rA, -3);
    LOAD_ROW(rB, -2);
    LOAD_ROW(rC, -1);
    LOAD_ROW(rD,  0);

    // crow0: rows (t0-3..t0-1) -> pos t0 wr=0; rA (t0-3) dies here
    CONV_ROW(rA, rB, rC, true, 0, false, 0);
    LOAD_ROW(rA, 1);                       // slot reuse: rA <- row t0+1
    // crow1: rows (t0-2..t0)   -> pos t0 wr=1, pos t0+1 wr=0
    CONV_ROW(rB, rC, rD, true, 1, true, 0);
    // crow2: rows (t0-1..t0+1) -> pos t0+1 wr=1
    CONV_ROW(rC, rD, rA, false, 0, true, 1);

    // ---- FC1 tanh -> FC2 for both positions ----
    float ya0 = fc_out_b[0], ya1 = fc_out_b[1];
    float yb0 = ya0, yb1 = ya1;
    #pragma unroll
    for (int j = 0; j < FC_HID; ++j) {
        const float w0 = fc_out_w[j];
        const float w1 = fc_out_w[FC_HID + j];
        const float ha = tanh_fast(h_a[j]);
        const float hb = tanh_fast(h_b[j]);
        ya0 = fmaf(ha, w0, ya0);
        ya1 = fmaf(ha, w1, ya1);
        yb0 = fmaf(hb, w0, yb0);
        yb1 = fmaf(hb, w1, yb1);
    }

    float4 o;
    o.x = ya0; o.y = ya1; o.z = yb0; o.w = yb1;
    reinterpret_cast<float4*>(out)[(b * TT + t0) >> 1] = o;

#undef LOAD_ROW
#undef CONV_ROW
}

extern "C" void kernel_launch(void* const* d_in, const int* in_sizes, int n_in,
                              void* d_out, int out_size, void* d_ws, size_t ws_size,
                              hipStream_t stream) {
    const float* x        = (const float*)d_in[0];
    const float* conv_w   = (const float*)d_in[1];
    const float* conv_b   = (const float*)d_in[2];
    const float* fc_hid_w = (const float*)d_in[3];
    const float* fc_hid_b = (const float*)d_in[4];
    const float* fc_out_w = (const float*)d_in[5];
    const float* fc_out_b = (const float*)d_in[6];
    float* out = (float*)d_out;

    const int n_pairs = BB * TT / 2;       // 262144 threads
    const int block = 256;
    const int grid = n_pairs / block;      // 1024 blocks = 4 blocks/CU, uniform
    rvtdcnn_fused4<<<grid, block, 0, stream>>>(x, conv_w, conv_b, fc_hid_w, fc_hid_b,
                                               fc_out_w, fc_out_b, out);
}